// Round 3
// baseline (218.545 us; speedup 1.0000x reference)
//
#include <hip/hip_runtime.h>
#include <math.h>
#include <stdint.h>

// tgate_hybrid: B=4,S=4096,DIMS=2048,T=10,K=2.
// R15: DRAM row-locality theory. Four load mechanisms (256B-visit staging,
// NT, direct-to-reg, 1KB-visit staging) all plateau ~2.2 TB/s; the two
// ~6.3-6.9 TB/s references (harness fill, m13 copy) are grid-stride kernels
// whose instantaneous chip-wide address window is one compact marching slab.
// All our variants instead gave block b a PRIVATE contiguous 128 KB slab
// (rows 16b..16b+15): at any instant ~1024 scattered stride-128K streams ->
// per-HBM-channel row-buffer thrash -> ~30% DRAM efficiency, independent of
// load mechanism. Single-variable fix: block b now owns rows {b + 1024*r},
// so in lockstep all blocks read within one compact 8 MB slab that marches
// through x. Body is R14 verbatim except the global row address and the
// out[] index. Per-row math / k-order / MFMA sequence / fold order are
// untouched -> every out[row] bit-identical -> absmax exactly 0.00390625.

#define NROWS   16384
#define DIMS_   2048
#define TT      10
#define RSTRIDE 1024   // = NROWS/16 blocks; row r of block b is b + r*RSTRIDE

typedef __attribute__((ext_vector_type(8))) short short8;
typedef __attribute__((ext_vector_type(4))) float f32x4;

__device__ __forceinline__ unsigned short bf16_rne(float f) {
    unsigned int u = __float_as_uint(f);
    unsigned int r = u + 0x7fffu + ((u >> 16) & 1u);
    return (unsigned short)(r >> 16);
}

// ---- k0: build B fragments (unchanged since R5; must stay identical).
__global__ __launch_bounds__(256)
void tgate_k0(const float* __restrict__ W_cls,
              const float* __restrict__ W_sparse,
              const float* __restrict__ W_gates,
              unsigned short* __restrict__ frag)
{
    int t = blockIdx.x * 256 + threadIdx.x;
    int K0   = t >> 7;
    int nt   = (t >> 6) & 1;
    int lane = t & 63;
    int n  = nt * 16 + (lane & 15);
    int kb = K0 * 32 + (lane >> 4) * 8;
    short8 hi, lo;
    #pragma unroll
    for (int j = 0; j < 8; ++j) {
        int k = kb + j;
        float w = 0.0f;
        if (n < 10)      w = W_cls[k * TT + n];
        else if (n < 20) w = W_sparse[k * TT + n - 10];
        else if (n < 30) w = W_gates[k * TT + n - 20];
        unsigned short h = bf16_rne(w);
        float back = __uint_as_float(((unsigned int)h) << 16);
        hi[j] = (short)h;
        lo[j] = (short)bf16_rne(w - back);
    }
    short8* fv = reinterpret_cast<short8*>(frag);
    fv[(K0 * 4 + nt * 2 + 0) * 64 + lane] = hi;
    fv[(K0 * 4 + nt * 2 + 1) * 64 + lane] = lo;
}

// stage one 16-row x 256-col chunk: 16 instrs, each 1 KB CONTIGUOUS within
// one x row (64 lanes x 16 B). Rows are RSTRIDE apart globally (interleaved
// ownership); LDS dest wave-uniform base + lane*16 -> row slot r at
// buf + r*260 (pitch 260 floats for bank spread).
__device__ __forceinline__ void stage_span(const float* __restrict__ x,
                                           float* buf, int rowb, int lane,
                                           int colf0)
{
    #pragma unroll
    for (int r = 0; r < 16; ++r) {
        const float* gp = x + (size_t)(rowb + r * RSTRIDE) * DIMS_ + colf0 + lane * 4;
        __builtin_amdgcn_global_load_lds(
            (const __attribute__((address_space(1))) void*)gp,
            (__attribute__((address_space(3))) void*)(buf + r * 260),
            16, 0, 0);
    }
}

// ---- k1: fused full-K MFMA GEMV, 1KB-visit LDS staging, interleaved rows
__global__ __launch_bounds__(256)
void tgate_k1(const float* __restrict__ x,
              const unsigned short* __restrict__ frag,
              const float* __restrict__ b_cls,
              const float* __restrict__ b_sparse,
              const float* __restrict__ b_gates,
              const float* __restrict__ alpha,
              float* __restrict__ out)
{
    // 4 waves x 16 rows x 260 floats = 66560 B; reused for red/fold (4752 f)
    __shared__ alignas(16) float smem[4 * 4160];

    const int tid   = threadIdx.x;
    const int lane  = tid & 63;
    const int wv    = __builtin_amdgcn_readfirstlane(tid >> 6);
    const int rowb  = blockIdx.x;        // base row; block owns rowb + r*RSTRIDE
    const int m     = lane & 15;
    const int quad  = lane >> 4;
    const int cbase = wv * 512;          // wave's contiguous 512-col span

    float* buf = smem + wv * 4160;
    const short8* fv    = reinterpret_cast<const short8*>(frag);
    const short8* fbase = fv + (16 * wv * 4) * 64 + lane;   // step k -> +(k*4+j)*64

    f32x4 acc[2][2];
    #pragma unroll
    for (int h = 0; h < 2; ++h) {
        acc[h][0] = (f32x4){0.f, 0.f, 0.f, 0.f};
        acc[h][1] = (f32x4){0.f, 0.f, 0.f, 0.f};
    }

    // ---- stage chunk A (cols cbase..cbase+256) FIRST (oldest vmem ops)
    stage_span(x, buf, rowb, lane, cbase);
    __builtin_amdgcn_sched_barrier(0);   // pin issue order: A before frag

    // frag prefetch for steps 0,1 (8 loads, L2-resident)
    short8 F[2][4];
    #pragma unroll
    for (int p = 0; p < 2; ++p) {
        #pragma unroll
        for (int j = 0; j < 4; ++j)
            F[p][j] = fbase[(p * 4 + j) * 64];
    }
    __builtin_amdgcn_sched_barrier(0);   // pin: frag issued after A, before wait

    // A fully landed when <=8 outstanding (the 8 frag loads)
    __builtin_amdgcn_s_waitcnt(0x0F78);  // vmcnt(8)
    __builtin_amdgcn_sched_barrier(0);   // no ds_read hoists above the wait

    #pragma unroll
    for (int k = 0; k < 16; ++k) {
        if (k == 8) {
            // all A ds_reads retired -> safe to overwrite buffer with B
            __builtin_amdgcn_s_waitcnt(0xC07F);  // lgkmcnt(0)
            __builtin_amdgcn_sched_barrier(0);
            stage_span(x, buf, rowb, lane, cbase + 256);
            __builtin_amdgcn_s_waitcnt(0x0F70);  // vmcnt(0): B (+frag 8,9) landed
            __builtin_amdgcn_sched_barrier(0);
        }
        const int h = k >> 3;
        const float* src = buf + m * 260 + (k & 7) * 32 + quad * 8;
        float4 b0 = *reinterpret_cast<const float4*>(src);
        float4 b1 = *reinterpret_cast<const float4*>(src + 4);
        float f[8] = {b0.x, b0.y, b0.z, b0.w, b1.x, b1.y, b1.z, b1.w};
        short8 ah, al;
        #pragma unroll
        for (int j = 0; j < 8; ++j) {
            unsigned short hh = bf16_rne(f[j]);               // rne hi (R5.. path)
            float back = __uint_as_float(((unsigned int)hh) << 16);
            ah[j] = (short)hh;
            al[j] = (short)bf16_rne(f[j] - back);
        }
        short8 h0 = F[k & 1][0], l0 = F[k & 1][1];
        short8 h1 = F[k & 1][2], l1 = F[k & 1][3];

        acc[h][0] = __builtin_amdgcn_mfma_f32_16x16x32_bf16(ah, h0, acc[h][0], 0, 0, 0);
        acc[h][0] = __builtin_amdgcn_mfma_f32_16x16x32_bf16(al, h0, acc[h][0], 0, 0, 0);
        acc[h][0] = __builtin_amdgcn_mfma_f32_16x16x32_bf16(ah, l0, acc[h][0], 0, 0, 0);
        acc[h][1] = __builtin_amdgcn_mfma_f32_16x16x32_bf16(ah, h1, acc[h][1], 0, 0, 0);
        acc[h][1] = __builtin_amdgcn_mfma_f32_16x16x32_bf16(al, h1, acc[h][1], 0, 0, 0);
        acc[h][1] = __builtin_amdgcn_mfma_f32_16x16x32_bf16(ah, l1, acc[h][1], 0, 0, 0);

        if (k + 2 < 16) {                 // refill frag slot (k&1) for step k+2
            #pragma unroll
            for (int j = 0; j < 4; ++j)
                F[k & 1][j] = fbase[((k + 2) * 4 + j) * 64];
        }
    }

    // ---- partials to LDS: red[s][row][j], pitch 33 (verbatim since R5;
    //      red aliases the staging buffer, valid after the barrier)
    float* red = smem;
    __syncthreads();
    #pragma unroll
    for (int h = 0; h < 2; ++h) {
        int s = 2 * wv + h;
        #pragma unroll
        for (int r = 0; r < 4; ++r) {
            int row = quad * 4 + r;       // C/D layout (verified m89)
            red[(s * 16 + row) * 33 + m]      = acc[h][0][r];
            red[(s * 16 + row) * 33 + m + 16] = acc[h][1][r];
        }
    }
    __syncthreads();

    // ---- fold: bit-identical (l=0; s=0..7 ascending)
    float* fold = red + 8 * 16 * 33;
    #pragma unroll
    for (int u = 0; u < 2; ++u) {
        int i = tid * 2 + u;
        int row = i >> 5, j = i & 31;
        float a = 0.0f;
        #pragma unroll
        for (int s = 0; s < 8; ++s) a += red[(s * 16 + row) * 33 + j];
        fold[row * 33 + j] = a;
    }
    __syncthreads();

    // ---- epilogue: lanes 0..15 of wave 0 (verbatim since R5; out index
    //      follows the interleaved row ownership: global row = rowb + tid*RSTRIDE)
    if (tid < 16) {
        const float* l = &fold[tid * 33];
        float lc[TT], lsp[TT], g[TT];
        #pragma unroll
        for (int t = 0; t < TT; ++t) {
            lc[t]  = l[t]      + b_cls[t];
            lsp[t] = l[10 + t] + b_sparse[t];
            float lg = l[20 + t] + b_gates[t];
            g[t] = 1.0f / (1.0f + __expf(-lg));
        }
        float mm = lc[0];
        #pragma unroll
        for (int t = 1; t < TT; ++t) mm = fmaxf(mm, lc[t]);
        float esum = 0.0f, gdot = 0.0f;
        #pragma unroll
        for (int t = 0; t < TT; ++t) {
            float e = __expf(lc[t] - mm);
            esum += e;
            gdot = fmaf(g[t], e, gdot);
        }
        float v1 = lsp[0], v2 = -1e30f, gv1 = g[0], gv2 = 0.0f;
        #pragma unroll
        for (int t = 1; t < TT; ++t) {
            if (lsp[t] > v1)      { v2 = v1; gv2 = gv1; v1 = lsp[t]; gv1 = g[t]; }
            else if (lsp[t] > v2) { v2 = lsp[t]; gv2 = g[t]; }
        }
        float s1 = 1.0f / (1.0f + __expf(v2 - v1));
        float s2 = 1.0f - s1;
        float a  = 1.0f / (1.0f + __expf(-alpha[0]));
        float sparse_dot = fmaf(gv1, s1, gv2 * s2);
        out[rowb + tid * RSTRIDE] = fmaf(a, sparse_dot, (1.0f - a) * (gdot / esum));
    }
}

extern "C" void kernel_launch(void* const* d_in, const int* in_sizes, int n_in,
                              void* d_out, int out_size, void* d_ws, size_t ws_size,
                              hipStream_t stream) {
    const float* x        = (const float*)d_in[0];
    const float* W_cls    = (const float*)d_in[1];
    const float* b_cls    = (const float*)d_in[2];
    const float* W_sparse = (const float*)d_in[3];
    const float* b_sparse = (const float*)d_in[4];
    const float* W_gates  = (const float*)d_in[5];
    const float* b_gates  = (const float*)d_in[6];
    const float* alpha    = (const float*)d_in[7];
    float* out = (float*)d_out;

    unsigned short* frag = (unsigned short*)d_ws;   // 256 KB

    tgate_k0<<<dim3(32), dim3(256), 0, stream>>>(W_cls, W_sparse, W_gates, frag);
    tgate_k1<<<dim3(NROWS / 16), dim3(256), 0, stream>>>(x, frag, b_cls, b_sparse,
                                                         b_gates, alpha, out);
}